// Round 1
// baseline (3896.409 us; speedup 1.0000x reference)
//
#include <hip/hip_runtime.h>
#include <hip/hip_bf16.h>

#define T 2048
#define E 64
#define H 64
#define VOCAB 50257
#define G3 192   // 3*H

__device__ __forceinline__ float sigmoidf_(float x) { return 1.0f / (1.0f + expf(-x)); }

// ---------------------------------------------------------------------------
// K1: x[t] = emb[data[t]]; gi_enc[t] = Wih_enc @ x[t] + bih_enc   (parallel)
// grid: T blocks x 192 threads
// ---------------------------------------------------------------------------
__global__ void __launch_bounds__(192) k_embed_gi(const int* __restrict__ data,
                                                  const float* __restrict__ emb,
                                                  const float* __restrict__ Wih,
                                                  const float* __restrict__ bih,
                                                  float* __restrict__ gi) {
    int t = blockIdx.x;
    int tid = threadIdx.x;
    __shared__ __align__(16) float x[E];
    if (tid < E) x[tid] = emb[(size_t)data[t] * E + tid];
    __syncthreads();
    const float4* w = (const float4*)(Wih + (size_t)tid * E);
    float acc = bih[tid];
    #pragma unroll
    for (int k = 0; k < E / 4; ++k) {
        float4 wv = w[k];
        float4 xv = *(const float4*)&x[4 * k];
        acc += wv.x * xv.x + wv.y * xv.y + wv.z * xv.z + wv.w * xv.w;
    }
    gi[(size_t)t * G3 + tid] = acc;
}

// ---------------------------------------------------------------------------
// K2: encoder GRU, serial over T steps. 1 block x 192 threads.
// Thread j holds Whh_enc row j (64 floats) in registers. h broadcast via LDS.
// ---------------------------------------------------------------------------
__global__ void __launch_bounds__(192) k_enc(const float* __restrict__ Whh,
                                             const float* __restrict__ bhh,
                                             const float* __restrict__ gi,
                                             float* __restrict__ h_out) {
    int j = threadIdx.x;
    float w[E];
    {
        const float4* wr = (const float4*)(Whh + (size_t)j * E);
        #pragma unroll
        for (int k = 0; k < E / 4; ++k) {
            float4 f = wr[k];
            w[4 * k] = f.x; w[4 * k + 1] = f.y; w[4 * k + 2] = f.z; w[4 * k + 3] = f.w;
        }
    }
    float bh = bhh[j];
    __shared__ __align__(16) float h[H];
    __shared__ float gh[G3];
    if (j < H) h[j] = 0.0f;
    __syncthreads();
    float hreg = 0.0f;   // valid for j < H
    for (int t = 0; t < T; ++t) {
        // issue gi loads early so latency overlaps the dot product
        float gir = 0.f, giz = 0.f, gin = 0.f;
        if (j < H) {
            const float* g = gi + (size_t)t * G3;
            gir = g[j]; giz = g[H + j]; gin = g[2 * H + j];
        }
        float acc = bh;
        #pragma unroll
        for (int k = 0; k < H / 4; ++k) {
            float4 hv = *(const float4*)&h[4 * k];
            acc += w[4 * k] * hv.x + w[4 * k + 1] * hv.y + w[4 * k + 2] * hv.z + w[4 * k + 3] * hv.w;
        }
        gh[j] = acc;
        __syncthreads();
        if (j < H) {
            float r = sigmoidf_(gir + gh[j]);
            float z = sigmoidf_(giz + gh[H + j]);
            float n = tanhf(gin + r * gh[2 * H + j]);
            hreg = (1.0f - z) * n + z * hreg;
            h[j] = hreg;
        }
        __syncthreads();
    }
    if (j < H) h_out[j] = hreg;
}

// ---------------------------------------------------------------------------
// K3: decoder GRU, serial over T steps. 1 block x 384 threads.
// threads [0,192): gi = Wih_dec @ inp ; threads [192,384): gh = Whh_dec @ hid
// ---------------------------------------------------------------------------
__global__ void __launch_bounds__(384) k_dec(const float* __restrict__ Wih,
                                             const float* __restrict__ Whh,
                                             const float* __restrict__ bih,
                                             const float* __restrict__ bhh,
                                             const float* __restrict__ h0,
                                             float* __restrict__ outs) {
    int tid = threadIdx.x;
    bool isG = tid < G3;
    int j = isG ? tid : tid - G3;
    const float* Wr = (isG ? Wih : Whh) + (size_t)j * H;
    float w[H];
    {
        const float4* wr = (const float4*)Wr;
        #pragma unroll
        for (int k = 0; k < H / 4; ++k) {
            float4 f = wr[k];
            w[4 * k] = f.x; w[4 * k + 1] = f.y; w[4 * k + 2] = f.z; w[4 * k + 3] = f.w;
        }
    }
    float b = isG ? bih[j] : bhh[j];
    __shared__ __align__(16) float inp[H];
    __shared__ __align__(16) float hid[H];
    __shared__ float gi[G3];
    __shared__ float gh[G3];
    if (tid < H) { inp[tid] = 0.0f; hid[tid] = h0[tid]; }
    __syncthreads();
    for (int t = 0; t < T; ++t) {
        const float* src = isG ? inp : hid;
        float acc = b;
        #pragma unroll
        for (int k = 0; k < H / 4; ++k) {
            float4 hv = *(const float4*)&src[4 * k];
            acc += w[4 * k] * hv.x + w[4 * k + 1] * hv.y + w[4 * k + 2] * hv.z + w[4 * k + 3] * hv.w;
        }
        (isG ? gi : gh)[j] = acc;
        __syncthreads();
        if (tid < H) {
            float r = sigmoidf_(gi[tid] + gh[tid]);
            float z = sigmoidf_(gi[H + tid] + gh[H + tid]);
            float n = tanhf(gi[2 * H + tid] + r * gh[2 * H + tid]);
            float o = (1.0f - z) * n + z * hid[tid];
            outs[(size_t)t * H + tid] = o;
            inp[tid] = o;
            hid[tid] = o;
        }
        __syncthreads();
    }
}

// ---------------------------------------------------------------------------
// K4: logits = outs @ W_out^T + b_out.  grid (197, 16) x 256 threads.
// Thread owns one vocab column v (W row in 64 VGPRs); outs chunk in LDS,
// broadcast reads.
// ---------------------------------------------------------------------------
#define PT 128
__global__ void __launch_bounds__(256) k_proj(const float* __restrict__ outs,
                                              const float* __restrict__ Wout,
                                              const float* __restrict__ bout,
                                              float* __restrict__ out) {
    __shared__ __align__(16) float s[PT * H];
    int t0 = blockIdx.y * PT;
    {
        const float4* src = (const float4*)(outs + (size_t)t0 * H);
        for (int i = threadIdx.x; i < PT * H / 4; i += 256) ((float4*)s)[i] = src[i];
    }
    __syncthreads();
    int v = blockIdx.x * 256 + threadIdx.x;
    bool valid = v < VOCAB;
    float w[H];
    float bias = 0.0f;
    if (valid) {
        const float4* wr = (const float4*)(Wout + (size_t)v * H);
        #pragma unroll
        for (int k = 0; k < H / 4; ++k) {
            float4 f = wr[k];
            w[4 * k] = f.x; w[4 * k + 1] = f.y; w[4 * k + 2] = f.z; w[4 * k + 3] = f.w;
        }
        bias = bout[v];
    }
    for (int tt = 0; tt < PT; tt += 8) {
        float acc[8];
        #pragma unroll
        for (int u = 0; u < 8; ++u) acc[u] = bias;
        #pragma unroll
        for (int k = 0; k < H / 4; ++k) {
            #pragma unroll
            for (int u = 0; u < 8; ++u) {
                float4 hv = *(const float4*)&s[(tt + u) * H + 4 * k];
                acc[u] += w[4 * k] * hv.x + w[4 * k + 1] * hv.y + w[4 * k + 2] * hv.z + w[4 * k + 3] * hv.w;
            }
        }
        if (valid) {
            size_t base = (size_t)(t0 + tt) * VOCAB + v;
            #pragma unroll
            for (int u = 0; u < 8; ++u) out[base + (size_t)u * VOCAB] = acc[u];
        }
    }
}

extern "C" void kernel_launch(void* const* d_in, const int* in_sizes, int n_in,
                              void* d_out, int out_size, void* d_ws, size_t ws_size,
                              hipStream_t stream) {
    const int*   data    = (const int*)d_in[0];
    // d_in[1] = Type (ignored; reference takes the map branch)
    const float* emb     = (const float*)d_in[2];
    const float* Wih_enc = (const float*)d_in[3];
    const float* Whh_enc = (const float*)d_in[4];
    const float* bih_enc = (const float*)d_in[5];
    const float* bhh_enc = (const float*)d_in[6];
    const float* Wih_dec = (const float*)d_in[7];
    const float* Whh_dec = (const float*)d_in[8];
    const float* bih_dec = (const float*)d_in[9];
    const float* bhh_dec = (const float*)d_in[10];
    const float* W_out   = (const float*)d_in[11];
    const float* b_out   = (const float*)d_in[12];
    float* out = (float*)d_out;

    float* gi_enc = (float*)d_ws;          // T*G3 floats
    float* outs   = gi_enc + (size_t)T * G3; // T*H floats
    float* h_enc  = outs + (size_t)T * H;    // H floats

    k_embed_gi<<<T, G3, 0, stream>>>(data, emb, Wih_enc, bih_enc, gi_enc);
    k_enc<<<1, G3, 0, stream>>>(Whh_enc, bhh_enc, gi_enc, h_enc);
    k_dec<<<1, 384, 0, stream>>>(Wih_dec, Whh_dec, bih_dec, bhh_dec, h_enc, outs);
    dim3 pgrid((VOCAB + 255) / 256, T / PT);
    k_proj<<<pgrid, 256, 0, stream>>>(outs, W_out, b_out, out);
}

// Round 3
// 3429.401 us; speedup vs baseline: 1.1362x; 1.1362x over previous
//
#include <hip/hip_runtime.h>
#include <hip/hip_bf16.h>

#define T 2048
#define E 64
#define H 64
#define VOCAB 50257
#define G3 192   // 3*H

__device__ __forceinline__ float sigmoidf_(float x) { return 1.0f / (1.0f + expf(-x)); }

// ---------------------------------------------------------------------------
// K1: x[t] = emb[data[t]]; gi_enc[t] = Wih_enc @ x[t] + bih_enc   (parallel)
// grid: T blocks x 192 threads
// ---------------------------------------------------------------------------
__global__ void __launch_bounds__(192) k_embed_gi(const int* __restrict__ data,
                                                  const float* __restrict__ emb,
                                                  const float* __restrict__ Wih,
                                                  const float* __restrict__ bih,
                                                  float* __restrict__ gi) {
    int t = blockIdx.x;
    int tid = threadIdx.x;
    __shared__ __align__(16) float x[E];
    if (tid < E) x[tid] = emb[(size_t)data[t] * E + tid];
    __syncthreads();
    const float4* w = (const float4*)(Wih + (size_t)tid * E);
    float acc = bih[tid];
    #pragma unroll
    for (int k = 0; k < E / 4; ++k) {
        float4 wv = w[k];
        float4 xv = *(const float4*)&x[4 * k];
        acc += wv.x * xv.x + wv.y * xv.y + wv.z * xv.z + wv.w * xv.w;
    }
    gi[(size_t)t * G3 + tid] = acc;
}

// ---------------------------------------------------------------------------
// K2: encoder GRU, single wave (64 lanes), barrier-free.
// Lane j holds Whh rows {j, j+64, j+128} in VGPRs (192 regs).
// h broadcast via LDS (same-wave ds_write -> ds_read, no s_barrier).
// gi[t+1] software-prefetched.
// ---------------------------------------------------------------------------
__global__ void __launch_bounds__(64, 1) k_enc(const float* __restrict__ Whh,
                                               const float* __restrict__ bhh,
                                               const float* __restrict__ gi,
                                               float* __restrict__ h_out) {
    int j = threadIdx.x;
    float wr[H], wz[H], wn[H];
    #pragma unroll
    for (int k = 0; k < H; k += 4) {
        float4 a = *(const float4*)(Whh + (size_t)j * H + k);
        float4 b = *(const float4*)(Whh + (size_t)(H + j) * H + k);
        float4 c = *(const float4*)(Whh + (size_t)(2 * H + j) * H + k);
        wr[k] = a.x; wr[k + 1] = a.y; wr[k + 2] = a.z; wr[k + 3] = a.w;
        wz[k] = b.x; wz[k + 1] = b.y; wz[k + 2] = b.z; wz[k + 3] = b.w;
        wn[k] = c.x; wn[k + 1] = c.y; wn[k + 2] = c.z; wn[k + 3] = c.w;
    }
    float br = bhh[j], bz = bhh[H + j], bn = bhh[2 * H + j];
    __shared__ __align__(16) float h[H];
    h[j] = 0.0f;
    float hj = 0.0f;
    // prefetch gi[0]
    float gir = gi[j], giz = gi[H + j], gin = gi[2 * H + j];
    for (int t = 0; t < T; ++t) {
        asm volatile("" ::: "memory");
        // prefetch next step's gi (consumed after the FMA block -> latency hidden)
        int tn = (t + 1 < T) ? t + 1 : t;
        const float* g = gi + (size_t)tn * G3;
        float gir2 = g[j], giz2 = g[H + j], gin2 = g[2 * H + j];
        float ar = br, az = bz, an = bn;
        #pragma unroll
        for (int k4 = 0; k4 < H / 4; ++k4) {
            float4 hv = ((const float4*)h)[k4];
            ar += wr[4 * k4 + 0] * hv.x; az += wz[4 * k4 + 0] * hv.x; an += wn[4 * k4 + 0] * hv.x;
            ar += wr[4 * k4 + 1] * hv.y; az += wz[4 * k4 + 1] * hv.y; an += wn[4 * k4 + 1] * hv.y;
            ar += wr[4 * k4 + 2] * hv.z; az += wz[4 * k4 + 2] * hv.z; an += wn[4 * k4 + 2] * hv.z;
            ar += wr[4 * k4 + 3] * hv.w; az += wz[4 * k4 + 3] * hv.w; an += wn[4 * k4 + 3] * hv.w;
        }
        float r = sigmoidf_(gir + ar);
        float z = sigmoidf_(giz + az);
        float n = tanhf(gin + r * an);
        hj = (1.0f - z) * n + z * hj;
        asm volatile("" ::: "memory");
        h[j] = hj;
        asm volatile("" ::: "memory");
        gir = gir2; giz = giz2; gin = gin2;
    }
    h_out[j] = hj;
}

// ---------------------------------------------------------------------------
// K3: decoder GRU, single wave (64 lanes), barrier-free.
// For t>=1: inp == hid == o_prev, so r/z gates use combined (Wih+Whh) rows.
// Lane j holds: wr=(Wih+Whh) row j, wz=(Wih+Whh) row H+j,
//               wi=Wih row 2H+j, wh=Whh row 2H+j  (256 VGPRs).
// t=0 (inp=0, hid=h_enc) folded into the weight-load loop.
// outs stores are fire-and-forget (no barrier ever waits on them).
// ---------------------------------------------------------------------------
__global__ void __launch_bounds__(64, 1) k_dec(const float* __restrict__ Wih,
                                               const float* __restrict__ Whh,
                                               const float* __restrict__ bih,
                                               const float* __restrict__ bhh,
                                               const float* __restrict__ h0,
                                               float* __restrict__ outs) {
    int j = threadIdx.x;
    float wr[H], wz[H], wi[H], wh[H];
    float ar0 = bhh[j], az0 = bhh[H + j], ah0 = bhh[2 * H + j];
    #pragma unroll
    for (int k = 0; k < H; k += 4) {
        float4 ir = *(const float4*)(Wih + (size_t)j * H + k);
        float4 hr = *(const float4*)(Whh + (size_t)j * H + k);
        float4 iz = *(const float4*)(Wih + (size_t)(H + j) * H + k);
        float4 hz = *(const float4*)(Whh + (size_t)(H + j) * H + k);
        float4 in_ = *(const float4*)(Wih + (size_t)(2 * H + j) * H + k);
        float4 hn = *(const float4*)(Whh + (size_t)(2 * H + j) * H + k);
        float4 he = *(const float4*)(h0 + k);   // uniform -> scalar loads
        // prologue (t=0): gh = Whh @ h_enc + bhh
        ar0 += hr.x * he.x + hr.y * he.y + hr.z * he.z + hr.w * he.w;
        az0 += hz.x * he.x + hz.y * he.y + hz.z * he.z + hz.w * he.w;
        ah0 += hn.x * he.x + hn.y * he.y + hn.z * he.z + hn.w * he.w;
        wr[k] = ir.x + hr.x; wr[k + 1] = ir.y + hr.y; wr[k + 2] = ir.z + hr.z; wr[k + 3] = ir.w + hr.w;
        wz[k] = iz.x + hz.x; wz[k + 1] = iz.y + hz.y; wz[k + 2] = iz.z + hz.z; wz[k + 3] = iz.w + hz.w;
        wi[k] = in_.x; wi[k + 1] = in_.y; wi[k + 2] = in_.z; wi[k + 3] = in_.w;
        wh[k] = hn.x; wh[k + 1] = hn.y; wh[k + 2] = hn.z; wh[k + 3] = hn.w;
    }
    float bir = bih[j], biz = bih[H + j];
    float bi = bih[2 * H + j], bh = bhh[2 * H + j];
    float brz_r = bir + bhh[j], brz_z = biz + bhh[H + j];

    __shared__ __align__(16) float h[H];
    // t = 0: gi = bih (Wih@0), gh computed above
    float r0 = sigmoidf_(bir + ar0);
    float z0 = sigmoidf_(biz + az0);
    float n0 = tanhf(bi + r0 * ah0);
    float oj = (1.0f - z0) * n0 + z0 * h0[j];
    outs[j] = oj;
    h[j] = oj;

    for (int t = 1; t < T; ++t) {
        asm volatile("" ::: "memory");
        float ar = brz_r, az = brz_z, ai = bi, ah = bh;
        #pragma unroll
        for (int k4 = 0; k4 < H / 4; ++k4) {
            float4 hv = ((const float4*)h)[k4];
            ar += wr[4 * k4 + 0] * hv.x; az += wz[4 * k4 + 0] * hv.x;
            ai += wi[4 * k4 + 0] * hv.x; ah += wh[4 * k4 + 0] * hv.x;
            ar += wr[4 * k4 + 1] * hv.y; az += wz[4 * k4 + 1] * hv.y;
            ai += wi[4 * k4 + 1] * hv.y; ah += wh[4 * k4 + 1] * hv.y;
            ar += wr[4 * k4 + 2] * hv.z; az += wz[4 * k4 + 2] * hv.z;
            ai += wi[4 * k4 + 2] * hv.z; ah += wh[4 * k4 + 2] * hv.z;
            ar += wr[4 * k4 + 3] * hv.w; az += wz[4 * k4 + 3] * hv.w;
            ai += wi[4 * k4 + 3] * hv.w; ah += wh[4 * k4 + 3] * hv.w;
        }
        float r = sigmoidf_(ar);
        float z = sigmoidf_(az);
        float n = tanhf(ai + r * ah);
        oj = (1.0f - z) * n + z * oj;
        outs[(size_t)t * H + j] = oj;   // fire-and-forget
        asm volatile("" ::: "memory");
        h[j] = oj;
        asm volatile("" ::: "memory");
    }
}

// ---------------------------------------------------------------------------
// K4: logits = outs @ W_out^T + b_out.  grid (197, 16) x 256 threads.
// ---------------------------------------------------------------------------
#define PT 128
__global__ void __launch_bounds__(256) k_proj(const float* __restrict__ outs,
                                              const float* __restrict__ Wout,
                                              const float* __restrict__ bout,
                                              float* __restrict__ out) {
    __shared__ __align__(16) float s[PT * H];
    int t0 = blockIdx.y * PT;
    {
        const float4* src = (const float4*)(outs + (size_t)t0 * H);
        for (int i = threadIdx.x; i < PT * H / 4; i += 256) ((float4*)s)[i] = src[i];
    }
    __syncthreads();
    int v = blockIdx.x * 256 + threadIdx.x;
    bool valid = v < VOCAB;
    float w[H];
    float bias = 0.0f;
    if (valid) {
        const float4* wr = (const float4*)(Wout + (size_t)v * H);
        #pragma unroll
        for (int k = 0; k < H / 4; ++k) {
            float4 f = wr[k];
            w[4 * k] = f.x; w[4 * k + 1] = f.y; w[4 * k + 2] = f.z; w[4 * k + 3] = f.w;
        }
        bias = bout[v];
    }
    for (int tt = 0; tt < PT; tt += 8) {
        float acc[8];
        #pragma unroll
        for (int u = 0; u < 8; ++u) acc[u] = bias;
        #pragma unroll
        for (int k = 0; k < H / 4; ++k) {
            #pragma unroll
            for (int u = 0; u < 8; ++u) {
                float4 hv = *(const float4*)&s[(tt + u) * H + 4 * k];
                acc[u] += w[4 * k] * hv.x + w[4 * k + 1] * hv.y + w[4 * k + 2] * hv.z + w[4 * k + 3] * hv.w;
            }
        }
        if (valid) {
            size_t base = (size_t)(t0 + tt) * VOCAB + v;
            #pragma unroll
            for (int u = 0; u < 8; ++u) out[base + (size_t)u * VOCAB] = acc[u];
        }
    }
}

extern "C" void kernel_launch(void* const* d_in, const int* in_sizes, int n_in,
                              void* d_out, int out_size, void* d_ws, size_t ws_size,
                              hipStream_t stream) {
    const int*   data    = (const int*)d_in[0];
    // d_in[1] = Type (ignored; reference takes the map branch)
    const float* emb     = (const float*)d_in[2];
    const float* Wih_enc = (const float*)d_in[3];
    const float* Whh_enc = (const float*)d_in[4];
    const float* bih_enc = (const float*)d_in[5];
    const float* bhh_enc = (const float*)d_in[6];
    const float* Wih_dec = (const float*)d_in[7];
    const float* Whh_dec = (const float*)d_in[8];
    const float* bih_dec = (const float*)d_in[9];
    const float* bhh_dec = (const float*)d_in[10];
    const float* W_out   = (const float*)d_in[11];
    const float* b_out   = (const float*)d_in[12];
    float* out = (float*)d_out;

    float* gi_enc = (float*)d_ws;            // T*G3 floats
    float* outs   = gi_enc + (size_t)T * G3; // T*H floats
    float* h_enc  = outs + (size_t)T * H;    // H floats

    k_embed_gi<<<T, G3, 0, stream>>>(data, emb, Wih_enc, bih_enc, gi_enc);
    k_enc<<<1, 64, 0, stream>>>(Whh_enc, bhh_enc, gi_enc, h_enc);
    k_dec<<<1, 64, 0, stream>>>(Wih_dec, Whh_dec, bih_dec, bhh_dec, h_enc, outs);
    dim3 pgrid((VOCAB + 255) / 256, T / PT);
    k_proj<<<pgrid, 256, 0, stream>>>(outs, W_out, b_out, out);
}

// Round 5
// 2813.724 us; speedup vs baseline: 1.3848x; 1.2188x over previous
//
#include <hip/hip_runtime.h>
#include <hip/hip_bf16.h>

#define T 2048
#define E 64
#define H 64
#define VOCAB 50257
#define G3 192   // 3*H

// fast activations: v_exp_f32 + v_rcp_f32 (err ~1e-6, threshold is 1.7e-2)
__device__ __forceinline__ float fsig(float x) {
    return __builtin_amdgcn_rcpf(1.f + __expf(-x));
}
__device__ __forceinline__ float ftanh(float x) {
    // (e^2x-1)/(e^2x+1); e->inf => 1, e->0 => -1, both exact
    float e = __expf(2.f * x);
    return 1.f - 2.f * __builtin_amdgcn_rcpf(e + 1.f);
}

// raw workgroup barrier: drain LDS ops, do NOT drain vmcnt (keeps global
// stores fire-and-forget, unlike __syncthreads()).
__device__ __forceinline__ void wgbar() {
    asm volatile("s_waitcnt lgkmcnt(0)" ::: "memory");
    __builtin_amdgcn_s_barrier();
    asm volatile("" ::: "memory");
}

// ---------------------------------------------------------------------------
// K1: x[t] = emb[data[t]]; gi_enc[t] = Wih_enc @ x[t] + bih_enc   (parallel)
// ---------------------------------------------------------------------------
__global__ void __launch_bounds__(192) k_embed_gi(const int* __restrict__ data,
                                                  const float* __restrict__ emb,
                                                  const float* __restrict__ Wih,
                                                  const float* __restrict__ bih,
                                                  float* __restrict__ gi) {
    int t = blockIdx.x;
    int tid = threadIdx.x;
    __shared__ __align__(16) float x[E];
    if (tid < E) x[tid] = emb[(size_t)data[t] * E + tid];
    __syncthreads();
    const float4* w = (const float4*)(Wih + (size_t)tid * E);
    float acc = bih[tid];
    #pragma unroll
    for (int k = 0; k < E / 4; ++k) {
        float4 wv = w[k];
        float4 xv = *(const float4*)&x[4 * k];
        acc += wv.x * xv.x + wv.y * xv.y + wv.z * xv.z + wv.w * xv.w;
    }
    gi[(size_t)t * G3 + tid] = acc;
}

// ---------------------------------------------------------------------------
// K2: encoder GRU. 3 waves; wave w owns gate-set w (r / z / n-hidden).
// Lane j of wave w holds Whh row (w*64+j) in 64 VGPRs. One raw barrier/step.
// Partials double-buffered by parity. gi[t+1] prefetched from L2 and folded.
// phase2: r=sig(p0), z=sig(p1), n=tanh(p3 + r*p2), h=(1-z)n+z*h.
// ---------------------------------------------------------------------------
__global__ void __launch_bounds__(192, 1) k_enc(const float* __restrict__ Whh,
                                                const float* __restrict__ bhh,
                                                const float* __restrict__ gi,
                                                float* __restrict__ h_out) {
    int tid = threadIdx.x;
    int w = tid >> 6, j = tid & 63;
    __shared__ __align__(16) float hs[H];
    __shared__ float pbuf[2][4 * H];

    const float* a = Whh + (size_t)(w * H + j) * H;
    float wrow[H];
    #pragma unroll
    for (int k = 0; k < H; k += 4) {
        float4 av = *(const float4*)(a + k);
        wrow[k] = av.x; wrow[k + 1] = av.y; wrow[k + 2] = av.z; wrow[k + 3] = av.w;
    }
    float bias = bhh[w * H + j];

    // t = 0: h = 0 -> gh = bias; fold gi[0]
    if (w == 0)      pbuf[0][j]         = bias + gi[j];
    else if (w == 1) pbuf[0][H + j]     = bias + gi[H + j];
    else {           pbuf[0][2 * H + j] = bias;
                     pbuf[0][3 * H + j] = gi[2 * H + j]; }
    float h = 0.f;
    wgbar();

    for (int t = 0; t < T; ++t) {
        const float* p = pbuf[t & 1];
        float p0 = p[j], p1 = p[H + j], p2 = p[2 * H + j], p3 = p[3 * H + j];
        float r = fsig(p0);
        float z = fsig(p1);
        float n = ftanh(p3 + r * p2);
        h = (1.f - z) * n + z * h;
        hs[j] = h;   // every wave writes the full h vector (identical values)
        if (t + 1 < T) {
            // prefetch next gi early (L2 hit ~200cy, hidden under the dot)
            float g = gi[(size_t)(t + 1) * G3 + w * H + j];
            float a0 = 0.f, a1 = 0.f, a2 = 0.f, a3 = 0.f;
            #pragma unroll
            for (int k4 = 0; k4 < H / 4; k4 += 4) {
                float4 h0v = ((const float4*)hs)[k4];
                float4 h1v = ((const float4*)hs)[k4 + 1];
                float4 h2v = ((const float4*)hs)[k4 + 2];
                float4 h3v = ((const float4*)hs)[k4 + 3];
                a0 += wrow[4*k4+0]*h0v.x + wrow[4*k4+1]*h0v.y + wrow[4*k4+2]*h0v.z + wrow[4*k4+3]*h0v.w;
                a1 += wrow[4*k4+4]*h1v.x + wrow[4*k4+5]*h1v.y + wrow[4*k4+6]*h1v.z + wrow[4*k4+7]*h1v.w;
                a2 += wrow[4*k4+8]*h2v.x + wrow[4*k4+9]*h2v.y + wrow[4*k4+10]*h2v.z + wrow[4*k4+11]*h2v.w;
                a3 += wrow[4*k4+12]*h3v.x + wrow[4*k4+13]*h3v.y + wrow[4*k4+14]*h3v.z + wrow[4*k4+15]*h3v.w;
            }
            float acc = bias + ((a0 + a1) + (a2 + a3));
            if (w < 2) acc += g;                       // fold gi_r / gi_z
            float* pn = pbuf[(t + 1) & 1];
            pn[w * H + j] = acc;                       // w==2 -> part2 = gh_n
            if (w == 2) pn[3 * H + j] = g;             // part3 = gi_n
        }
        wgbar();
    }
    if (w == 0) h_out[j] = h;
}

// ---------------------------------------------------------------------------
// K3: decoder GRU. 4 waves; wave w owns: 0 -> combined (Wih+Whh) r-rows,
// 1 -> combined z-rows, 2 -> Wih n-rows, 3 -> Whh n-rows (valid since
// inp==hid==o_prev for t>=1). t=0 (inp=0, hid=h_enc) partials computed in
// the weight-load prologue. One raw barrier per step; outs fire-and-forget.
// phase2: r=sig(p0), z=sig(p1), n=tanh(p2 + r*p3), o=(1-z)n+z*o.
// ---------------------------------------------------------------------------
__global__ void __launch_bounds__(256, 1) k_dec(const float* __restrict__ Wih,
                                                const float* __restrict__ Whh,
                                                const float* __restrict__ bih,
                                                const float* __restrict__ bhh,
                                                const float* __restrict__ h0,
                                                float* __restrict__ outs) {
    int tid = threadIdx.x;
    int w = tid >> 6, j = tid & 63;
    __shared__ __align__(16) float hs[H];
    __shared__ float pbuf[2][4 * H];

    int rowi = (w == 1) ? H + j : (w >= 2 ? 2 * H + j : j);
    const float* a  = ((w == 3) ? Whh : Wih) + (size_t)rowi * H;
    const float* bm = Whh + (size_t)rowi * H;
    float wrow[H];
    float pacc = 0.f;
    #pragma unroll
    for (int k = 0; k < H; k += 4) {
        float4 av = *(const float4*)(a + k);
        float4 he = *(const float4*)(h0 + k);   // lane-uniform -> scalar loads
        if (w < 2) {
            float4 bv = *(const float4*)(bm + k);
            pacc += bv.x * he.x + bv.y * he.y + bv.z * he.z + bv.w * he.w;
            av.x += bv.x; av.y += bv.y; av.z += bv.z; av.w += bv.w;
        } else if (w == 3) {
            pacc += av.x * he.x + av.y * he.y + av.z * he.z + av.w * he.w;
        }
        wrow[k] = av.x; wrow[k + 1] = av.y; wrow[k + 2] = av.z; wrow[k + 3] = av.w;
    }
    float bias = (w == 0) ? bih[j] + bhh[j]
               : (w == 1) ? bih[H + j] + bhh[H + j]
               : (w == 2) ? bih[2 * H + j]
                          : bhh[2 * H + j];
    float o = h0[j];
    pbuf[0][w * H + j] = bias + pacc;   // t=0 partials
    wgbar();

    for (int t = 0; t < T; ++t) {
        const float* p = pbuf[t & 1];
        float p0 = p[j], p1 = p[H + j], p2 = p[2 * H + j], p3 = p[3 * H + j];
        float r = fsig(p0);
        float z = fsig(p1);
        float n = ftanh(p2 + r * p3);
        o = (1.f - z) * n + z * o;
        hs[j] = o;                       // all waves write identical values
        if (w == 0) outs[(size_t)t * H + j] = o;   // fire-and-forget
        if (t + 1 < T) {
            float a0 = 0.f, a1 = 0.f, a2 = 0.f, a3 = 0.f;
            #pragma unroll
            for (int k4 = 0; k4 < H / 4; k4 += 4) {
                float4 h0v = ((const float4*)hs)[k4];
                float4 h1v = ((const float4*)hs)[k4 + 1];
                float4 h2v = ((const float4*)hs)[k4 + 2];
                float4 h3v = ((const float4*)hs)[k4 + 3];
                a0 += wrow[4*k4+0]*h0v.x + wrow[4*k4+1]*h0v.y + wrow[4*k4+2]*h0v.z + wrow[4*k4+3]*h0v.w;
                a1 += wrow[4*k4+4]*h1v.x + wrow[4*k4+5]*h1v.y + wrow[4*k4+6]*h1v.z + wrow[4*k4+7]*h1v.w;
                a2 += wrow[4*k4+8]*h2v.x + wrow[4*k4+9]*h2v.y + wrow[4*k4+10]*h2v.z + wrow[4*k4+11]*h2v.w;
                a3 += wrow[4*k4+12]*h3v.x + wrow[4*k4+13]*h3v.y + wrow[4*k4+14]*h3v.z + wrow[4*k4+15]*h3v.w;
            }
            pbuf[(t + 1) & 1][w * H + j] = bias + ((a0 + a1) + (a2 + a3));
        }
        wgbar();
    }
}

// ---------------------------------------------------------------------------
// K4: logits = outs @ W_out^T + b_out.  grid (197, 16) x 256 threads.
// ---------------------------------------------------------------------------
#define PT 128
__global__ void __launch_bounds__(256) k_proj(const float* __restrict__ outs,
                                              const float* __restrict__ Wout,
                                              const float* __restrict__ bout,
                                              float* __restrict__ out) {
    __shared__ __align__(16) float s[PT * H];
    int t0 = blockIdx.y * PT;
    {
        const float4* src = (const float4*)(outs + (size_t)t0 * H);
        for (int i = threadIdx.x; i < PT * H / 4; i += 256) ((float4*)s)[i] = src[i];
    }
    __syncthreads();
    int v = blockIdx.x * 256 + threadIdx.x;
    bool valid = v < VOCAB;
    float w[H];
    float bias = 0.0f;
    if (valid) {
        const float4* wr = (const float4*)(Wout + (size_t)v * H);
        #pragma unroll
        for (int k = 0; k < H / 4; ++k) {
            float4 f = wr[k];
            w[4 * k] = f.x; w[4 * k + 1] = f.y; w[4 * k + 2] = f.z; w[4 * k + 3] = f.w;
        }
        bias = bout[v];
    }
    for (int tt = 0; tt < PT; tt += 8) {
        float acc[8];
        #pragma unroll
        for (int u = 0; u < 8; ++u) acc[u] = bias;
        #pragma unroll
        for (int k = 0; k < H / 4; ++k) {
            #pragma unroll
            for (int u = 0; u < 8; ++u) {
                float4 hv = *(const float4*)&s[(tt + u) * H + 4 * k];
                acc[u] += w[4 * k] * hv.x + w[4 * k + 1] * hv.y + w[4 * k + 2] * hv.z + w[4 * k + 3] * hv.w;
            }
        }
        if (valid) {
            size_t base = (size_t)(t0 + tt) * VOCAB + v;
            #pragma unroll
            for (int u = 0; u < 8; ++u) out[base + (size_t)u * VOCAB] = acc[u];
        }
    }
}

extern "C" void kernel_launch(void* const* d_in, const int* in_sizes, int n_in,
                              void* d_out, int out_size, void* d_ws, size_t ws_size,
                              hipStream_t stream) {
    const int*   data    = (const int*)d_in[0];
    // d_in[1] = Type (ignored; reference takes the map branch)
    const float* emb     = (const float*)d_in[2];
    const float* Wih_enc = (const float*)d_in[3];
    const float* Whh_enc = (const float*)d_in[4];
    const float* bih_enc = (const float*)d_in[5];
    const float* bhh_enc = (const float*)d_in[6];
    const float* Wih_dec = (const float*)d_in[7];
    const float* Whh_dec = (const float*)d_in[8];
    const float* bih_dec = (const float*)d_in[9];
    const float* bhh_dec = (const float*)d_in[10];
    const float* W_out   = (const float*)d_in[11];
    const float* b_out   = (const float*)d_in[12];
    float* out = (float*)d_out;

    float* gi_enc = (float*)d_ws;            // T*G3 floats
    float* outs   = gi_enc + (size_t)T * G3; // T*H floats
    float* h_enc  = outs + (size_t)T * H;    // H floats

    k_embed_gi<<<T, G3, 0, stream>>>(data, emb, Wih_enc, bih_enc, gi_enc);
    k_enc<<<1, 192, 0, stream>>>(Whh_enc, bhh_enc, gi_enc, h_enc);
    k_dec<<<1, 256, 0, stream>>>(Wih_dec, Whh_dec, bih_dec, bhh_dec, h_enc, outs);
    dim3 pgrid((VOCAB + 255) / 256, T / PT);
    k_proj<<<pgrid, 256, 0, stream>>>(outs, W_out, b_out, out);
}

// Round 7
// 2264.546 us; speedup vs baseline: 1.7206x; 1.2425x over previous
//
#include <hip/hip_runtime.h>
#include <hip/hip_bf16.h>

#define T 2048
#define E 64
#define H 64
#define VOCAB 50257
#define G3 192   // 3*H

// fast activations: v_exp_f32 + v_rcp_f32 (err ~1e-6, threshold is 1.7e-2)
__device__ __forceinline__ float fsig(float x) {
    return __builtin_amdgcn_rcpf(1.f + __expf(-x));
}
__device__ __forceinline__ float ftanh(float x) {
    float e = __expf(2.f * x);
    return 1.f - 2.f * __builtin_amdgcn_rcpf(e + 1.f);
}

// raw workgroup barrier: drain LDS ops, do NOT drain vmcnt (keeps global
// stores fire-and-forget, unlike __syncthreads()).
__device__ __forceinline__ void wgbar() {
    asm volatile("s_waitcnt lgkmcnt(0)" ::: "memory");
    __builtin_amdgcn_s_barrier();
    asm volatile("" ::: "memory");
}

// pin a float in a VGPR: value becomes the result of an opaque asm op, so the
// backend can neither rematerialize the originating load nor fold it away.
#define PIN(x) asm volatile("" : "+v"(x))

// ---------------------------------------------------------------------------
// K1: x[t] = emb[data[t]]; gi_enc[t] = Wih_enc @ x[t] + bih_enc   (parallel)
// ---------------------------------------------------------------------------
__global__ void __launch_bounds__(192) k_embed_gi(const int* __restrict__ data,
                                                  const float* __restrict__ emb,
                                                  const float* __restrict__ Wih,
                                                  const float* __restrict__ bih,
                                                  float* __restrict__ gi) {
    int t = blockIdx.x;
    int tid = threadIdx.x;
    __shared__ __align__(16) float x[E];
    if (tid < E) x[tid] = emb[(size_t)data[t] * E + tid];
    __syncthreads();
    const float4* w = (const float4*)(Wih + (size_t)tid * E);
    float acc = bih[tid];
    #pragma unroll
    for (int k = 0; k < E / 4; ++k) {
        float4 wv = w[k];
        float4 xv = *(const float4*)&x[4 * k];
        acc += wv.x * xv.x + wv.y * xv.y + wv.z * xv.z + wv.w * xv.w;
    }
    gi[(size_t)t * G3 + tid] = acc;
}

// ---------------------------------------------------------------------------
// K2: encoder GRU. 3 waves; wave w owns gate-set w (r / z / n-hidden).
// Lane j of wave w holds Whh row (w*64+j) PINNED in 64 VGPRs.
// One raw barrier/step; partials double-buffered; gi prefetched 2 steps deep.
// phase2: r=sig(p0), z=sig(p1), n=tanh(p3 + r*p2), h=(1-z)n+z*h.
// ---------------------------------------------------------------------------
__global__ void __launch_bounds__(192)
__attribute__((amdgpu_waves_per_eu(1, 1)))
k_enc(const float* __restrict__ Whh,
      const float* __restrict__ bhh,
      const float* __restrict__ gi,
      float* __restrict__ h_out) {
    int tid = threadIdx.x;
    int w = tid >> 6, j = tid & 63;
    __shared__ __align__(16) float hs[H];
    __shared__ float pbuf[2][4 * H];

    const float* a = Whh + (size_t)(w * H + j) * H;
    float wrow[H];
    #pragma unroll
    for (int k = 0; k < H; k += 4) {
        float4 av = *(const float4*)(a + k);
        wrow[k] = av.x; wrow[k + 1] = av.y; wrow[k + 2] = av.z; wrow[k + 3] = av.w;
    }
    #pragma unroll
    for (int k = 0; k < H; ++k) PIN(wrow[k]);
    float bias = bhh[w * H + j];

    // t = 0: h = 0 -> gh = bias; fold gi[0]
    if (w == 0)      pbuf[0][j]         = bias + gi[j];
    else if (w == 1) pbuf[0][H + j]     = bias + gi[H + j];
    else {           pbuf[0][2 * H + j] = bias;
                     pbuf[0][3 * H + j] = gi[2 * H + j]; }
    float h = 0.f;
    float g1 = gi[(size_t)G3 + w * H + j];   // gi for t=1
    wgbar();

    for (int t = 0; t < T; ++t) {
        const float* p = pbuf[t & 1];
        float p0 = p[j], p1 = p[H + j], p2 = p[2 * H + j], p3 = p[3 * H + j];
        float r = fsig(p0);
        float z = fsig(p1);
        float n = ftanh(p3 + r * p2);
        h = (1.f - z) * n + z * h;
        hs[j] = h;   // every wave writes the full h vector (identical values)
        if (t + 1 < T) {
            int t2 = (t + 2 < T) ? t + 2 : t + 1;     // prefetch depth 2
            float g2 = gi[(size_t)t2 * G3 + w * H + j];
            float a0=0.f,a1=0.f,a2=0.f,a3=0.f,a4=0.f,a5=0.f,a6=0.f,a7=0.f;
            #pragma unroll
            for (int q = 0; q < 8; ++q) {
                float4 hv0 = ((const float4*)hs)[q];
                float4 hv1 = ((const float4*)hs)[q + 8];
                float t0 = wrow[4*q+0]*hv0.x + wrow[4*q+1]*hv0.y
                         + wrow[4*q+2]*hv0.z + wrow[4*q+3]*hv0.w;
                float t1 = wrow[32+4*q+0]*hv1.x + wrow[32+4*q+1]*hv1.y
                         + wrow[32+4*q+2]*hv1.z + wrow[32+4*q+3]*hv1.w;
                switch (q & 3) {
                    case 0: a0 += t0; a4 += t1; break;
                    case 1: a1 += t0; a5 += t1; break;
                    case 2: a2 += t0; a6 += t1; break;
                    default: a3 += t0; a7 += t1; break;
                }
            }
            float acc = bias + (((a0+a1)+(a2+a3)) + ((a4+a5)+(a6+a7)));
            if (w < 2) acc += g1;                      // fold gi_r / gi_z
            float* pn = pbuf[(t + 1) & 1];
            pn[w * H + j] = acc;                       // w==2 -> part2 = gh_n
            if (w == 2) pn[3 * H + j] = g1;            // part3 = gi_n
            g1 = g2;
        }
        wgbar();
    }
    if (w == 0) h_out[j] = h;
}

// ---------------------------------------------------------------------------
// K3: decoder GRU. 4 waves; wave w owns: 0 -> combined (Wih+Whh) r-rows,
// 1 -> combined z-rows, 2 -> Wih n-rows, 3 -> Whh n-rows (valid since
// inp==hid==o_prev for t>=1). Row PINNED in 64 VGPRs. t=0 (inp=0, hid=h_enc)
// partials in the prologue. One raw barrier/step; outs fire-and-forget.
// phase2: r=sig(p0), z=sig(p1), n=tanh(p2 + r*p3), o=(1-z)n+z*o.
// ---------------------------------------------------------------------------
__global__ void __launch_bounds__(256)
__attribute__((amdgpu_waves_per_eu(1, 1)))
k_dec(const float* __restrict__ Wih,
      const float* __restrict__ Whh,
      const float* __restrict__ bih,
      const float* __restrict__ bhh,
      const float* __restrict__ h0,
      float* __restrict__ outs) {
    int tid = threadIdx.x;
    int w = tid >> 6, j = tid & 63;
    __shared__ __align__(16) float hs[H];
    __shared__ float pbuf[2][4 * H];

    int rowi = (w == 1) ? H + j : (w >= 2 ? 2 * H + j : j);
    const float* a  = ((w == 3) ? Whh : Wih) + (size_t)rowi * H;
    const float* bm = Whh + (size_t)rowi * H;
    float wrow[H];
    float pacc = 0.f;
    #pragma unroll
    for (int k = 0; k < H; k += 4) {
        float4 av = *(const float4*)(a + k);
        float4 he = *(const float4*)(h0 + k);   // lane-uniform -> scalar loads
        if (w < 2) {
            float4 bv = *(const float4*)(bm + k);
            pacc += bv.x * he.x + bv.y * he.y + bv.z * he.z + bv.w * he.w;
            av.x += bv.x; av.y += bv.y; av.z += bv.z; av.w += bv.w;
        } else if (w == 3) {
            pacc += av.x * he.x + av.y * he.y + av.z * he.z + av.w * he.w;
        }
        wrow[k] = av.x; wrow[k + 1] = av.y; wrow[k + 2] = av.z; wrow[k + 3] = av.w;
    }
    #pragma unroll
    for (int k = 0; k < H; ++k) PIN(wrow[k]);
    float bias = (w == 0) ? bih[j] + bhh[j]
               : (w == 1) ? bih[H + j] + bhh[H + j]
               : (w == 2) ? bih[2 * H + j]
                          : bhh[2 * H + j];
    float o = h0[j];
    pbuf[0][w * H + j] = bias + pacc;   // t=0 partials
    wgbar();

    for (int t = 0; t < T; ++t) {
        const float* p = pbuf[t & 1];
        float p0 = p[j], p1 = p[H + j], p2 = p[2 * H + j], p3 = p[3 * H + j];
        float r = fsig(p0);
        float z = fsig(p1);
        float n = ftanh(p2 + r * p3);
        o = (1.f - z) * n + z * o;
        hs[j] = o;                       // all waves write identical values
        if (w == 0) outs[(size_t)t * H + j] = o;   // fire-and-forget
        if (t + 1 < T) {
            float a0=0.f,a1=0.f,a2=0.f,a3=0.f,a4=0.f,a5=0.f,a6=0.f,a7=0.f;
            #pragma unroll
            for (int q = 0; q < 8; ++q) {
                float4 hv0 = ((const float4*)hs)[q];
                float4 hv1 = ((const float4*)hs)[q + 8];
                float t0 = wrow[4*q+0]*hv0.x + wrow[4*q+1]*hv0.y
                         + wrow[4*q+2]*hv0.z + wrow[4*q+3]*hv0.w;
                float t1 = wrow[32+4*q+0]*hv1.x + wrow[32+4*q+1]*hv1.y
                         + wrow[32+4*q+2]*hv1.z + wrow[32+4*q+3]*hv1.w;
                switch (q & 3) {
                    case 0: a0 += t0; a4 += t1; break;
                    case 1: a1 += t0; a5 += t1; break;
                    case 2: a2 += t0; a6 += t1; break;
                    default: a3 += t0; a7 += t1; break;
                }
            }
            pbuf[(t + 1) & 1][w * H + j] =
                bias + (((a0+a1)+(a2+a3)) + ((a4+a5)+(a6+a7)));
        }
        wgbar();
    }
}

// ---------------------------------------------------------------------------
// K4: logits = outs @ W_out^T + b_out.  grid (197, 16) x 256 threads.
// ---------------------------------------------------------------------------
#define PT 128
__global__ void __launch_bounds__(256) k_proj(const float* __restrict__ outs,
                                              const float* __restrict__ Wout,
                                              const float* __restrict__ bout,
                                              float* __restrict__ out) {
    __shared__ __align__(16) float s[PT * H];
    int t0 = blockIdx.y * PT;
    {
        const float4* src = (const float4*)(outs + (size_t)t0 * H);
        for (int i = threadIdx.x; i < PT * H / 4; i += 256) ((float4*)s)[i] = src[i];
    }
    __syncthreads();
    int v = blockIdx.x * 256 + threadIdx.x;
    bool valid = v < VOCAB;
    float w[H];
    float bias = 0.0f;
    if (valid) {
        const float4* wr = (const float4*)(Wout + (size_t)v * H);
        #pragma unroll
        for (int k = 0; k < H / 4; ++k) {
            float4 f = wr[k];
            w[4 * k] = f.x; w[4 * k + 1] = f.y; w[4 * k + 2] = f.z; w[4 * k + 3] = f.w;
        }
        bias = bout[v];
    }
    for (int tt = 0; tt < PT; tt += 8) {
        float acc[8];
        #pragma unroll
        for (int u = 0; u < 8; ++u) acc[u] = bias;
        #pragma unroll
        for (int k = 0; k < H / 4; ++k) {
            #pragma unroll
            for (int u = 0; u < 8; ++u) {
                float4 hv = *(const float4*)&s[(tt + u) * H + 4 * k];
                acc[u] += w[4 * k] * hv.x + w[4 * k + 1] * hv.y + w[4 * k + 2] * hv.z + w[4 * k + 3] * hv.w;
            }
        }
        if (valid) {
            size_t base = (size_t)(t0 + tt) * VOCAB + v;
            #pragma unroll
            for (int u = 0; u < 8; ++u) out[base + (size_t)u * VOCAB] = acc[u];
        }
    }
}

extern "C" void kernel_launch(void* const* d_in, const int* in_sizes, int n_in,
                              void* d_out, int out_size, void* d_ws, size_t ws_size,
                              hipStream_t stream) {
    const int*   data    = (const int*)d_in[0];
    // d_in[1] = Type (ignored; reference takes the map branch)
    const float* emb     = (const float*)d_in[2];
    const float* Wih_enc = (const float*)d_in[3];
    const float* Whh_enc = (const float*)d_in[4];
    const float* bih_enc = (const float*)d_in[5];
    const float* bhh_enc = (const float*)d_in[6];
    const float* Wih_dec = (const float*)d_in[7];
    const float* Whh_dec = (const float*)d_in[8];
    const float* bih_dec = (const float*)d_in[9];
    const float* bhh_dec = (const float*)d_in[10];
    const float* W_out   = (const float*)d_in[11];
    const float* b_out   = (const float*)d_in[12];
    float* out = (float*)d_out;

    float* gi_enc = (float*)d_ws;            // T*G3 floats
    float* outs   = gi_enc + (size_t)T * G3; // T*H floats
    float* h_enc  = outs + (size_t)T * H;    // H floats

    k_embed_gi<<<T, G3, 0, stream>>>(data, emb, Wih_enc, bih_enc, gi_enc);
    k_enc<<<1, 192, 0, stream>>>(Whh_enc, bhh_enc, gi_enc, h_enc);
    k_dec<<<1, 256, 0, stream>>>(Wih_dec, Whh_dec, bih_dec, bhh_dec, h_enc, outs);
    dim3 pgrid((VOCAB + 255) / 256, T / PT);
    k_proj<<<pgrid, 256, 0, stream>>>(outs, W_out, b_out, out);
}

// Round 8
// 2065.561 us; speedup vs baseline: 1.8864x; 1.0963x over previous
//
#include <hip/hip_runtime.h>
#include <hip/hip_bf16.h>

#define T 2048
#define E 64
#define H 64
#define VOCAB 50257
#define G3 192   // 3*H

typedef float f32x2 __attribute__((ext_vector_type(2)));

// fast activations: v_exp_f32 + v_rcp_f32 (err ~1e-6, threshold is 1.7e-2)
__device__ __forceinline__ float fsig(float x) {
    return __builtin_amdgcn_rcpf(1.f + __expf(-x));
}
__device__ __forceinline__ float ftanh(float x) {
    float e = __expf(2.f * x);
    return 1.f - 2.f * __builtin_amdgcn_rcpf(e + 1.f);
}

// raw workgroup barrier: drain LDS ops, do NOT drain vmcnt (keeps global
// stores fire-and-forget, unlike __syncthreads()).
__device__ __forceinline__ void wgbar() {
    asm volatile("s_waitcnt lgkmcnt(0)" ::: "memory");
    __builtin_amdgcn_s_barrier();
    asm volatile("" ::: "memory");
}

// pin a value in VGPRs: becomes the result of an opaque asm op, so the
// backend can neither rematerialize the originating load nor spill-refold it.
#define PIN(x) asm volatile("" : "+v"(x))

// packed dot helper: acc pairs over 64-float row held as 32 f32x2
#define DOT64_PK(W2, HSP)                                        \
    f32x2 a0 = {0.f, 0.f}, a1 = {0.f, 0.f},                      \
          a2 = {0.f, 0.f}, a3 = {0.f, 0.f};                      \
    _Pragma("unroll")                                            \
    for (int q = 0; q < 8; ++q) {                                \
        float4 hv = ((const float4*)(HSP))[q];                   \
        float4 hw = ((const float4*)(HSP))[q + 8];               \
        f32x2 hA = {hv.x, hv.y}, hB = {hv.z, hv.w};              \
        f32x2 hC = {hw.x, hw.y}, hD = {hw.z, hw.w};              \
        a0 += (W2)[2 * q] * hA;                                  \
        a1 += (W2)[2 * q + 1] * hB;                               \
        a2 += (W2)[16 + 2 * q] * hC;                              \
        a3 += (W2)[16 + 2 * q + 1] * hD;                          \
    }                                                            \
    f32x2 s2 = (a0 + a1) + (a2 + a3);                            \
    float dot = s2.x + s2.y;

// ---------------------------------------------------------------------------
// K1: x[t] = emb[data[t]]; gi_enc[t] = Wih_enc @ x[t] + bih_enc   (parallel)
// ---------------------------------------------------------------------------
__global__ void __launch_bounds__(192) k_embed_gi(const int* __restrict__ data,
                                                  const float* __restrict__ emb,
                                                  const float* __restrict__ Wih,
                                                  const float* __restrict__ bih,
                                                  float* __restrict__ gi) {
    int t = blockIdx.x;
    int tid = threadIdx.x;
    __shared__ __align__(16) float x[E];
    if (tid < E) x[tid] = emb[(size_t)data[t] * E + tid];
    __syncthreads();
    const float4* w = (const float4*)(Wih + (size_t)tid * E);
    float acc = bih[tid];
    #pragma unroll
    for (int k = 0; k < E / 4; ++k) {
        float4 wv = w[k];
        float4 xv = *(const float4*)&x[4 * k];
        acc += wv.x * xv.x + wv.y * xv.y + wv.z * xv.z + wv.w * xv.w;
    }
    gi[(size_t)t * G3 + tid] = acc;
}

// ---------------------------------------------------------------------------
// K2: encoder GRU. 3 waves; wave w owns gate-set w (r / z / n-hidden).
// Lane j of wave w holds Whh row (w*64+j) PINNED as 32 f32x2 (pk-math dot).
// One raw barrier/step; partials double-buffered; gi prefetched 2 steps deep.
// phase2: r=sig(p0), z=sig(p1), n=tanh(p3 + r*p2), h=(1-z)n+z*h.
// ---------------------------------------------------------------------------
__global__ void __launch_bounds__(192)
__attribute__((amdgpu_waves_per_eu(1, 1)))
k_enc(const float* __restrict__ Whh,
      const float* __restrict__ bhh,
      const float* __restrict__ gi,
      float* __restrict__ h_out) {
    int tid = threadIdx.x;
    int w = tid >> 6, j = tid & 63;
    __shared__ __align__(16) float hs[H];
    __shared__ float pbuf[2][4 * H];

    const float* a = Whh + (size_t)(w * H + j) * H;
    f32x2 w2[32];
    #pragma unroll
    for (int m = 0; m < 16; ++m) {
        float4 av = ((const float4*)a)[m];
        w2[2 * m] = (f32x2){av.x, av.y};
        w2[2 * m + 1] = (f32x2){av.z, av.w};
    }
    #pragma unroll
    for (int m = 0; m < 32; ++m) PIN(w2[m]);
    float bias = bhh[w * H + j];

    // t = 0: h = 0 -> gh = bias; fold gi[0]
    if (w == 0)      pbuf[0][j]         = bias + gi[j];
    else if (w == 1) pbuf[0][H + j]     = bias + gi[H + j];
    else {           pbuf[0][2 * H + j] = bias;
                     pbuf[0][3 * H + j] = gi[2 * H + j]; }
    float h = 0.f;
    float g1 = gi[(size_t)G3 + w * H + j];   // gi for t=1
    wgbar();

    for (int t = 0; t < T; ++t) {
        const float* p = pbuf[t & 1];
        float p0 = p[j], p1 = p[H + j], p2 = p[2 * H + j], p3 = p[3 * H + j];
        float r = fsig(p0);
        float z = fsig(p1);
        float n = ftanh(p3 + r * p2);
        h = (1.f - z) * n + z * h;
        hs[j] = h;   // every wave writes the full h vector (identical values)
        if (t + 1 < T) {
            int t2 = (t + 2 < T) ? t + 2 : t + 1;     // prefetch depth 2
            float g2 = gi[(size_t)t2 * G3 + w * H + j];
            DOT64_PK(w2, hs);
            float acc = bias + dot;
            if (w < 2) acc += g1;                      // fold gi_r / gi_z
            float* pn = pbuf[(t + 1) & 1];
            pn[w * H + j] = acc;                       // w==2 -> part2 = gh_n
            if (w == 2) pn[3 * H + j] = g1;            // part3 = gi_n
            g1 = g2;
        }
        wgbar();
    }
    if (w == 0) h_out[j] = h;
}

// ---------------------------------------------------------------------------
// K3: decoder GRU. 4 waves; wave w owns: 0 -> combined (Wih+Whh) r-rows,
// 1 -> combined z-rows, 2 -> Wih n-rows, 3 -> Whh n-rows (valid since
// inp==hid==o_prev for t>=1). Row PINNED as 32 f32x2. t=0 (inp=0, hid=h_enc)
// partials in the prologue. One raw barrier/step; outs fire-and-forget.
// phase2: r=sig(p0), z=sig(p1), n=tanh(p2 + r*p3), o=(1-z)n+z*o.
// ---------------------------------------------------------------------------
__global__ void __launch_bounds__(256)
__attribute__((amdgpu_waves_per_eu(1, 1)))
k_dec(const float* __restrict__ Wih,
      const float* __restrict__ Whh,
      const float* __restrict__ bih,
      const float* __restrict__ bhh,
      const float* __restrict__ h0,
      float* __restrict__ outs) {
    int tid = threadIdx.x;
    int w = tid >> 6, j = tid & 63;
    __shared__ __align__(16) float hs[H];
    __shared__ float pbuf[2][4 * H];

    int rowi = (w == 1) ? H + j : (w >= 2 ? 2 * H + j : j);
    const float* a  = ((w == 3) ? Whh : Wih) + (size_t)rowi * H;
    const float* bm = Whh + (size_t)rowi * H;
    f32x2 w2[32];
    float pacc = 0.f;
    #pragma unroll
    for (int k = 0; k < H; k += 4) {
        float4 av = *(const float4*)(a + k);
        float4 he = *(const float4*)(h0 + k);   // lane-uniform -> scalar loads
        if (w < 2) {
            float4 bv = *(const float4*)(bm + k);
            pacc += bv.x * he.x + bv.y * he.y + bv.z * he.z + bv.w * he.w;
            av.x += bv.x; av.y += bv.y; av.z += bv.z; av.w += bv.w;
        } else if (w == 3) {
            pacc += av.x * he.x + av.y * he.y + av.z * he.z + av.w * he.w;
        }
        w2[k / 2] = (f32x2){av.x, av.y};
        w2[k / 2 + 1] = (f32x2){av.z, av.w};
    }
    #pragma unroll
    for (int m = 0; m < 32; ++m) PIN(w2[m]);
    float bias = (w == 0) ? bih[j] + bhh[j]
               : (w == 1) ? bih[H + j] + bhh[H + j]
               : (w == 2) ? bih[2 * H + j]
                          : bhh[2 * H + j];
    float o = h0[j];
    pbuf[0][w * H + j] = bias + pacc;   // t=0 partials
    wgbar();

    for (int t = 0; t < T; ++t) {
        const float* p = pbuf[t & 1];
        float p0 = p[j], p1 = p[H + j], p2 = p[2 * H + j], p3 = p[3 * H + j];
        float r = fsig(p0);
        float z = fsig(p1);
        float n = ftanh(p2 + r * p3);
        o = (1.f - z) * n + z * o;
        hs[j] = o;                       // all waves write identical values
        if (w == 0) outs[(size_t)t * H + j] = o;   // fire-and-forget
        if (t + 1 < T) {
            DOT64_PK(w2, hs);
            pbuf[(t + 1) & 1][w * H + j] = bias + dot;
        }
        wgbar();
    }
}

// ---------------------------------------------------------------------------
// K4: logits = outs @ W_out^T + b_out.  grid (197, 2) x 256 threads.
// Each block keeps its W rows + bias in regs and sweeps CH=8 chunks of
// PT=128 timesteps, cutting W_out re-reads 16x -> 2x.
// ---------------------------------------------------------------------------
#define PT 128
#define CH 8
__global__ void __launch_bounds__(256) k_proj(const float* __restrict__ outs,
                                              const float* __restrict__ Wout,
                                              const float* __restrict__ bout,
                                              float* __restrict__ out) {
    __shared__ __align__(16) float s[PT * H];
    int v = blockIdx.x * 256 + threadIdx.x;
    bool valid = v < VOCAB;
    float w[H];
    float bias = 0.0f;
    if (valid) {
        const float4* wr = (const float4*)(Wout + (size_t)v * H);
        #pragma unroll
        for (int k = 0; k < H / 4; ++k) {
            float4 f = wr[k];
            w[4 * k] = f.x; w[4 * k + 1] = f.y; w[4 * k + 2] = f.z; w[4 * k + 3] = f.w;
        }
        bias = bout[v];
    }
    int t00 = blockIdx.y * (PT * CH);
    for (int c = 0; c < CH; ++c) {
        int t0 = t00 + c * PT;
        __syncthreads();   // previous chunk's reads done before overwrite
        {
            const float4* src = (const float4*)(outs + (size_t)t0 * H);
            for (int i = threadIdx.x; i < PT * H / 4; i += 256) ((float4*)s)[i] = src[i];
        }
        __syncthreads();
        for (int tt = 0; tt < PT; tt += 8) {
            float acc[8];
            #pragma unroll
            for (int u = 0; u < 8; ++u) acc[u] = bias;
            #pragma unroll
            for (int k = 0; k < H / 4; ++k) {
                #pragma unroll
                for (int u = 0; u < 8; ++u) {
                    float4 hv = *(const float4*)&s[(tt + u) * H + 4 * k];
                    acc[u] += w[4 * k] * hv.x + w[4 * k + 1] * hv.y + w[4 * k + 2] * hv.z + w[4 * k + 3] * hv.w;
                }
            }
            if (valid) {
                size_t base = (size_t)(t0 + tt) * VOCAB + v;
                #pragma unroll
                for (int u = 0; u < 8; ++u) out[base + (size_t)u * VOCAB] = acc[u];
            }
        }
    }
}

extern "C" void kernel_launch(void* const* d_in, const int* in_sizes, int n_in,
                              void* d_out, int out_size, void* d_ws, size_t ws_size,
                              hipStream_t stream) {
    const int*   data    = (const int*)d_in[0];
    // d_in[1] = Type (ignored; reference takes the map branch)
    const float* emb     = (const float*)d_in[2];
    const float* Wih_enc = (const float*)d_in[3];
    const float* Whh_enc = (const float*)d_in[4];
    const float* bih_enc = (const float*)d_in[5];
    const float* bhh_enc = (const float*)d_in[6];
    const float* Wih_dec = (const float*)d_in[7];
    const float* Whh_dec = (const float*)d_in[8];
    const float* bih_dec = (const float*)d_in[9];
    const float* bhh_dec = (const float*)d_in[10];
    const float* W_out   = (const float*)d_in[11];
    const float* b_out   = (const float*)d_in[12];
    float* out = (float*)d_out;

    float* gi_enc = (float*)d_ws;            // T*G3 floats
    float* outs   = gi_enc + (size_t)T * G3; // T*H floats
    float* h_enc  = outs + (size_t)T * H;    // H floats

    k_embed_gi<<<T, G3, 0, stream>>>(data, emb, Wih_enc, bih_enc, gi_enc);
    k_enc<<<1, 192, 0, stream>>>(Whh_enc, bhh_enc, gi_enc, h_enc);
    k_dec<<<1, 256, 0, stream>>>(Wih_dec, Whh_dec, bih_dec, bhh_dec, h_enc, outs);
    dim3 pgrid((VOCAB + 255) / 256, T / (PT * CH));
    k_proj<<<pgrid, 256, 0, stream>>>(outs, W_out, b_out, out);
}

// Round 9
// 1713.345 us; speedup vs baseline: 2.2742x; 1.2056x over previous
//
#include <hip/hip_runtime.h>
#include <hip/hip_bf16.h>

#define T 2048
#define E 64
#define H 64
#define VOCAB 50257
#define G3 192   // 3*H

typedef float f32x2 __attribute__((ext_vector_type(2)));

// fast activations: v_exp_f32 + v_rcp_f32 (err ~1e-6, threshold is 1.7e-2)
__device__ __forceinline__ float fsig(float x) {
    return __builtin_amdgcn_rcpf(1.f + __expf(-x));
}
__device__ __forceinline__ float ftanh(float x) {
    float e = __expf(2.f * x);
    return 1.f - 2.f * __builtin_amdgcn_rcpf(e + 1.f);
}

// raw workgroup barrier: drain LDS ops, do NOT drain vmcnt (keeps global
// stores fire-and-forget, unlike __syncthreads()).
__device__ __forceinline__ void wgbar() {
    asm volatile("s_waitcnt lgkmcnt(0)" ::: "memory");
    __builtin_amdgcn_s_barrier();
    asm volatile("" ::: "memory");
}

// pin a value in VGPRs (opaque asm op: no remat, no spill-refold)
#define PIN(x) asm volatile("" : "+v"(x))

// quad broadcast via DPP: all 4 lanes of a quad get lane-k's value (VALU lat)
#define QB(v, CTRL) \
    __int_as_float(__builtin_amdgcn_update_dpp(0, __float_as_int(v), CTRL, 0xF, 0xF, false))

// packed dot: 64-float row (32 f32x2, pinned) . hs[0..63] (LDS, broadcast reads)
#define DOT64_PK(W2, HSP)                                        \
    f32x2 a0 = {0.f, 0.f}, a1 = {0.f, 0.f},                      \
          a2 = {0.f, 0.f}, a3 = {0.f, 0.f};                      \
    _Pragma("unroll")                                            \
    for (int q = 0; q < 8; ++q) {                                \
        float4 hv = ((const float4*)(HSP))[q];                   \
        float4 hw = ((const float4*)(HSP))[q + 8];               \
        f32x2 hA = {hv.x, hv.y}, hB = {hv.z, hv.w};              \
        f32x2 hC = {hw.x, hw.y}, hD = {hw.z, hw.w};              \
        a0 += (W2)[2 * q] * hA;                                  \
        a1 += (W2)[2 * q + 1] * hB;                               \
        a2 += (W2)[16 + 2 * q] * hC;                              \
        a3 += (W2)[16 + 2 * q + 1] * hD;                          \
    }                                                            \
    f32x2 s2 = (a0 + a1) + (a2 + a3);                            \
    float dot = s2.x + s2.y;

// ---------------------------------------------------------------------------
// K1: x[t] = emb[data[t]]; gi_enc[t] = Wih_enc @ x[t] + bih_enc   (parallel)
// ---------------------------------------------------------------------------
__global__ void __launch_bounds__(192) k_embed_gi(const int* __restrict__ data,
                                                  const float* __restrict__ emb,
                                                  const float* __restrict__ Wih,
                                                  const float* __restrict__ bih,
                                                  float* __restrict__ gi) {
    int t = blockIdx.x;
    int tid = threadIdx.x;
    __shared__ __align__(16) float x[E];
    if (tid < E) x[tid] = emb[(size_t)data[t] * E + tid];
    __syncthreads();
    const float4* w = (const float4*)(Wih + (size_t)tid * E);
    float acc = bih[tid];
    #pragma unroll
    for (int k = 0; k < E / 4; ++k) {
        float4 wv = w[k];
        float4 xv = *(const float4*)&x[4 * k];
        acc += wv.x * xv.x + wv.y * xv.y + wv.z * xv.z + wv.w * xv.w;
    }
    gi[(size_t)t * G3 + tid] = acc;
}

// ---------------------------------------------------------------------------
// K2: encoder GRU, row-quad layout. 256 threads; lane = (row r = tid>>2,
// gate g = tid&3). g0/g1/g2 hold Whh rows r / H+r / 2H+r (pinned f32x2);
// g3 holds a zero row and streams gi_n. Gate exchange via DPP quad_perm
// (no LDS). One hs broadcast + one barrier per step; hs double-buffered.
// n = tanh(gi_n + r*gh_n); h = (1-z)n + z*h.
// ---------------------------------------------------------------------------
__global__ void __launch_bounds__(256)
__attribute__((amdgpu_waves_per_eu(1, 1)))
k_enc(const float* __restrict__ Whh,
      const float* __restrict__ bhh,
      const float* __restrict__ gi,
      float* __restrict__ h_out) {
    int tid = threadIdx.x;
    int r = tid >> 2, g = tid & 3;
    __shared__ __align__(16) float hs[2][H];

    f32x2 w2[32];
    float bias;
    if (g < 3) {
        const float* a = Whh + (size_t)(g * H + r) * H;
        #pragma unroll
        for (int m = 0; m < 16; ++m) {
            float4 av = ((const float4*)a)[m];
            w2[2 * m] = (f32x2){av.x, av.y};
            w2[2 * m + 1] = (f32x2){av.z, av.w};
        }
        bias = bhh[g * H + r];
    } else {
        #pragma unroll
        for (int m = 0; m < 32; ++m) w2[m] = (f32x2){0.f, 0.f};
        bias = 0.f;
    }
    #pragma unroll
    for (int m = 0; m < 32; ++m) PIN(w2[m]);

    // per-lane gi stream: g0 -> gi_r, g1 -> gi_z, g3 -> gi_n, g2 -> masked 0
    const float* gp = gi + r + ((g == 1) ? H : (g == 3) ? 2 * H : 0);
    float gm = (g == 2) ? 0.f : 1.f;
    float gcur = gm * gp[0];

    if (g == 0) hs[0][r] = 0.f;     // h_{-1} = 0
    float h = 0.f;
    wgbar();

    for (int t = 0; t < T; ++t) {
        int tn = (t + 1 < T) ? t + 1 : T - 1;
        float gnxt = gm * gp[(size_t)tn * G3];     // prefetch, used next iter
        DOT64_PK(w2, hs[t & 1]);
        float val = bias + dot + gcur;
        float v0 = QB(val, 0x00), v1 = QB(val, 0x55);
        float v2 = QB(val, 0xAA), v3 = QB(val, 0xFF);
        float rr = fsig(v0);
        float z  = fsig(v1);
        float n  = ftanh(v3 + rr * v2);    // v3 = gi_n, v2 = gh_n
        h = (1.f - z) * n + z * h;
        if (g == 0) hs[(t + 1) & 1][r] = h;
        gcur = gnxt;
        wgbar();
    }
    if (g == 0) h_out[r] = h;
}

// ---------------------------------------------------------------------------
// K3: decoder GRU, row-quad layout. 256 threads; lane = (row, gate).
// Since inp==hid==o_prev for t>=1: g0=(Wih+Whh)_r, g1=(Wih+Whh)_z,
// g2=Wih_n, g3=Whh_n (pinned). t=0 (inp=0, hid=h0) in the prologue.
// DPP gate exchange; one hs broadcast + one barrier per step; outs
// fire-and-forget. n = tanh(v2 + r*v3); o = (1-z)n + z*o.
// ---------------------------------------------------------------------------
__global__ void __launch_bounds__(256)
__attribute__((amdgpu_waves_per_eu(1, 1)))
k_dec(const float* __restrict__ Wih,
      const float* __restrict__ Whh,
      const float* __restrict__ bih,
      const float* __restrict__ bhh,
      const float* __restrict__ h0,
      float* __restrict__ outs) {
    int tid = threadIdx.x;
    int r = tid >> 2, g = tid & 3;
    __shared__ __align__(16) float hs[2][H];

    int idx = ((g == 0) ? 0 : (g == 1) ? H : 2 * H) + r;
    const float* ai = Wih + (size_t)idx * H;
    const float* ah = Whh + (size_t)idx * H;
    const float4 z4 = {0.f, 0.f, 0.f, 0.f};
    f32x2 w2[32];
    float pacc = 0.f;
    #pragma unroll
    for (int k = 0; k < H; k += 4) {
        float4 iv = (g == 3) ? z4 : *(const float4*)(ai + k);
        float4 hv = (g == 2) ? z4 : *(const float4*)(ah + k);
        float4 he = *(const float4*)(h0 + k);   // lane-uniform
        pacc += hv.x * he.x + hv.y * he.y + hv.z * he.z + hv.w * he.w;
        float4 wv = {iv.x + hv.x, iv.y + hv.y, iv.z + hv.z, iv.w + hv.w};
        w2[k / 2]     = (f32x2){wv.x, wv.y};
        w2[k / 2 + 1] = (f32x2){wv.z, wv.w};
    }
    #pragma unroll
    for (int m = 0; m < 32; ++m) PIN(w2[m]);
    float bias = ((g == 3) ? 0.f : bih[idx]) + ((g == 2) ? 0.f : bhh[idx]);

    // t = 0: inp = 0, hid = h0 -> val = bias + (Whh part)·h0
    float o;
    {
        float val = bias + pacc;
        float v0 = QB(val, 0x00), v1 = QB(val, 0x55);
        float v2 = QB(val, 0xAA), v3 = QB(val, 0xFF);
        float rr = fsig(v0);
        float z  = fsig(v1);
        float n  = ftanh(v2 + rr * v3);
        o = (1.f - z) * n + z * h0[r];
        if (g == 0) { outs[r] = o; hs[1][r] = o; }
    }
    wgbar();

    for (int t = 1; t < T; ++t) {
        DOT64_PK(w2, hs[t & 1]);
        float val = bias + dot;
        float v0 = QB(val, 0x00), v1 = QB(val, 0x55);
        float v2 = QB(val, 0xAA), v3 = QB(val, 0xFF);
        float rr = fsig(v0);
        float z  = fsig(v1);
        float n  = ftanh(v2 + rr * v3);    // v2 = gi_n side, v3 = gh_n side
        o = (1.f - z) * n + z * o;
        if (g == 0) { outs[(size_t)t * H + r] = o; hs[(t + 1) & 1][r] = o; }
        wgbar();
    }
}

// ---------------------------------------------------------------------------
// K4: logits = outs @ W_out^T + b_out.  grid (197, 16) x 256 threads.
// (reverted to the proven high-TLP shape; CH-chunking regressed)
// ---------------------------------------------------------------------------
#define PT 128
__global__ void __launch_bounds__(256) k_proj(const float* __restrict__ outs,
                                              const float* __restrict__ Wout,
                                              const float* __restrict__ bout,
                                              float* __restrict__ out) {
    __shared__ __align__(16) float s[PT * H];
    int t0 = blockIdx.y * PT;
    {
        const float4* src = (const float4*)(outs + (size_t)t0 * H);
        for (int i = threadIdx.x; i < PT * H / 4; i += 256) ((float4*)s)[i] = src[i];
    }
    __syncthreads();
    int v = blockIdx.x * 256 + threadIdx.x;
    bool valid = v < VOCAB;
    float w[H];
    float bias = 0.0f;
    if (valid) {
        const float4* wr = (const float4*)(Wout + (size_t)v * H);
        #pragma unroll
        for (int k = 0; k < H / 4; ++k) {
            float4 f = wr[k];
            w[4 * k] = f.x; w[4 * k + 1] = f.y; w[4 * k + 2] = f.z; w[4 * k + 3] = f.w;
        }
        bias = bout[v];
    }
    for (int tt = 0; tt < PT; tt += 8) {
        float acc[8];
        #pragma unroll
        for (int u = 0; u < 8; ++u) acc[u] = bias;
        #pragma unroll
        for (int k = 0; k < H / 4; ++k) {
            #pragma unroll
            for (int u = 0; u < 8; ++u) {
                float4 hv = *(const float4*)&s[(tt + u) * H + 4 * k];
                acc[u] += w[4 * k] * hv.x + w[4 * k + 1] * hv.y + w[4 * k + 2] * hv.z + w[4 * k + 3] * hv.w;
            }
        }
        if (valid) {
            size_t base = (size_t)(t0 + tt) * VOCAB + v;
            #pragma unroll
            for (int u = 0; u < 8; ++u) out[base + (size_t)u * VOCAB] = acc[u];
        }
    }
}

extern "C" void kernel_launch(void* const* d_in, const int* in_sizes, int n_in,
                              void* d_out, int out_size, void* d_ws, size_t ws_size,
                              hipStream_t stream) {
    const int*   data    = (const int*)d_in[0];
    // d_in[1] = Type (ignored; reference takes the map branch)
    const float* emb     = (const float*)d_in[2];
    const float* Wih_enc = (const float*)d_in[3];
    const float* Whh_enc = (const float*)d_in[4];
    const float* bih_enc = (const float*)d_in[5];
    const float* bhh_enc = (const float*)d_in[6];
    const float* Wih_dec = (const float*)d_in[7];
    const float* Whh_dec = (const float*)d_in[8];
    const float* bih_dec = (const float*)d_in[9];
    const float* bhh_dec = (const float*)d_in[10];
    const float* W_out   = (const float*)d_in[11];
    const float* b_out   = (const float*)d_in[12];
    float* out = (float*)d_out;

    float* gi_enc = (float*)d_ws;            // T*G3 floats
    float* outs   = gi_enc + (size_t)T * G3; // T*H floats
    float* h_enc  = outs + (size_t)T * H;    // H floats

    k_embed_gi<<<T, G3, 0, stream>>>(data, emb, Wih_enc, bih_enc, gi_enc);
    k_enc<<<1, 256, 0, stream>>>(Whh_enc, bhh_enc, gi_enc, h_enc);
    k_dec<<<1, 256, 0, stream>>>(Wih_dec, Whh_dec, bih_dec, bhh_dec, h_enc, outs);
    dim3 pgrid((VOCAB + 255) / 256, T / PT);
    k_proj<<<pgrid, 256, 0, stream>>>(outs, W_out, b_out, out);
}

// Round 10
// 1423.670 us; speedup vs baseline: 2.7369x; 1.2035x over previous
//
#include <hip/hip_runtime.h>
#include <hip/hip_bf16.h>

#define T 2048
#define E 64
#define H 64
#define VOCAB 50257
#define G3 192   // 3*H

typedef float f32x2 __attribute__((ext_vector_type(2)));

// fast activations: v_exp_f32 + v_rcp_f32 (err ~1e-6, threshold is 1.7e-2)
__device__ __forceinline__ float fsig(float x) {
    return __builtin_amdgcn_rcpf(1.f + __expf(-x));
}
__device__ __forceinline__ float ftanh(float x) {
    float e = __expf(2.f * x);
    return 1.f - 2.f * __builtin_amdgcn_rcpf(e + 1.f);
}

// raw workgroup barrier: drain LDS ops, do NOT drain vmcnt.
__device__ __forceinline__ void wgbar() {
    asm volatile("s_waitcnt lgkmcnt(0)" ::: "memory");
    __builtin_amdgcn_s_barrier();
    asm volatile("" ::: "memory");
}

// pin a value in VGPRs (opaque asm op: no remat, no spill-refold)
#define PIN(x) asm volatile("" : "+v"(x))

// quad butterfly add stage: x += x(lane ^ k) within each quad
#define DPPADD(x, CTRL) \
    x += __int_as_float(__builtin_amdgcn_update_dpp(0, __float_as_int(x), CTRL, 0xF, 0xF, false))
#define QUAD_REDUCE(x) do { DPPADD(x, 0xB1); DPPADD(x, 0x4E); } while (0)

// ---------------------------------------------------------------------------
// K1: x[t] = emb[data[t]]; gi_enc[t] = Wih_enc @ x[t] + bih_enc   (parallel)
// ---------------------------------------------------------------------------
__global__ void __launch_bounds__(192) k_embed_gi(const int* __restrict__ data,
                                                  const float* __restrict__ emb,
                                                  const float* __restrict__ Wih,
                                                  const float* __restrict__ bih,
                                                  float* __restrict__ gi) {
    int t = blockIdx.x;
    int tid = threadIdx.x;
    __shared__ __align__(16) float x[E];
    if (tid < E) x[tid] = emb[(size_t)data[t] * E + tid];
    __syncthreads();
    const float4* w = (const float4*)(Wih + (size_t)tid * E);
    float acc = bih[tid];
    #pragma unroll
    for (int k = 0; k < E / 4; ++k) {
        float4 wv = w[k];
        float4 xv = *(const float4*)&x[4 * k];
        acc += wv.x * xv.x + wv.y * xv.y + wv.z * xv.z + wv.w * xv.w;
    }
    gi[(size_t)t * G3 + tid] = acc;
}

// quarter-dot: lane holds quarter g (16 floats = 8 f32x2) of each of 4 gate
// rows in W2[q*8 .. q*8+7]; reads its 16-float h quarter (4 b128) and
// accumulates 4 partial dots.
#define QDOT(W2, HSP, P0, P1, P2, P3)                         \
    do {                                                      \
        _Pragma("unroll")                                     \
        for (int m = 0; m < 4; ++m) {                         \
            float4 hv = ((const float4*)(HSP))[4 * g + m];    \
            f32x2 hA = {hv.x, hv.y}, hB = {hv.z, hv.w};       \
            P0 += (W2)[2 * m] * hA;      P0 += (W2)[2 * m + 1] * hB;      \
            P1 += (W2)[8 + 2 * m] * hA;  P1 += (W2)[8 + 2 * m + 1] * hB;  \
            P2 += (W2)[16 + 2 * m] * hA; P2 += (W2)[16 + 2 * m + 1] * hB; \
            P3 += (W2)[24 + 2 * m] * hA; P3 += (W2)[24 + 2 * m + 1] * hB; \
        }                                                     \
    } while (0)

// ---------------------------------------------------------------------------
// K2: encoder GRU, quarter-split row-quad. 256 threads; lane = (row r, part g).
// Lane holds quarter g of Whh rows {r, H+r, 2H+r} (q3 = zero row, carries the
// streamed gi_n). Partial dots quad-reduced via DPP butterfly (no LDS for
// gate exchange); h broadcast is 4 ds_read_b128/lane (quarter only).
// r=sig(v0), z=sig(v1), n=tanh(v3 + r*v2); h=(1-z)n+z*h.
// ---------------------------------------------------------------------------
__global__ void __launch_bounds__(256)
__attribute__((amdgpu_waves_per_eu(1, 1)))
k_enc(const float* __restrict__ Whh,
      const float* __restrict__ bhh,
      const float* __restrict__ gi,
      float* __restrict__ h_out) {
    int tid = threadIdx.x;
    int r = tid >> 2, g = tid & 3;
    __shared__ __align__(16) float hs[2][H];

    int col0 = g * 16;
    f32x2 w2[32];
    #pragma unroll
    for (int m = 0; m < 4; ++m) {
        float4 q0 = *(const float4*)(Whh + (size_t)r * H + col0 + 4 * m);
        float4 q1 = *(const float4*)(Whh + (size_t)(H + r) * H + col0 + 4 * m);
        float4 q2 = *(const float4*)(Whh + (size_t)(2 * H + r) * H + col0 + 4 * m);
        w2[2 * m]     = (f32x2){q0.x, q0.y}; w2[2 * m + 1]     = (f32x2){q0.z, q0.w};
        w2[8 + 2 * m] = (f32x2){q1.x, q1.y}; w2[8 + 2 * m + 1] = (f32x2){q1.z, q1.w};
        w2[16 + 2 * m] = (f32x2){q2.x, q2.y}; w2[16 + 2 * m + 1] = (f32x2){q2.z, q2.w};
        w2[24 + 2 * m] = (f32x2){0.f, 0.f};  w2[24 + 2 * m + 1] = (f32x2){0.f, 0.f};
    }
    #pragma unroll
    for (int m = 0; m < 32; ++m) PIN(w2[m]);
    float b0 = bhh[r], b1 = bhh[H + r], b2 = bhh[2 * H + r];

    // gi stream: lane g==0 -> gi_r, g==1 -> gi_z, g==3 -> gi_n, g==2 unused
    const float* gp = gi + r + ((g == 1) ? H : (g == 3) ? 2 * H : 0);
    float c0 = (g == 0) ? 1.f : 0.f;
    float c1 = (g == 1) ? 1.f : 0.f;
    float c3 = (g == 3) ? 1.f : 0.f;
    float gcur = gp[0];

    if (g == 0) hs[0][r] = 0.f;     // h_{-1} = 0
    float h = 0.f;
    wgbar();

    for (int t = 0; t < T; ++t) {
        int tn = (t + 1 < T) ? t + 1 : T - 1;
        float gnxt = gp[(size_t)tn * G3];          // prefetch, used next iter
        f32x2 p0 = {0.f, 0.f}, p1 = {0.f, 0.f}, p2 = {0.f, 0.f}, p3 = {0.f, 0.f};
        QDOT(w2, hs[t & 1], p0, p1, p2, p3);
        float s0 = p0.x + p0.y + c0 * gcur;
        float s1 = p1.x + p1.y + c1 * gcur;
        float s2 = p2.x + p2.y;
        float s3 = p3.x + p3.y + c3 * gcur;
        QUAD_REDUCE(s0); QUAD_REDUCE(s1); QUAD_REDUCE(s2); QUAD_REDUCE(s3);
        float rr = fsig(s0 + b0);
        float z  = fsig(s1 + b1);
        float n  = ftanh(s3 + rr * (s2 + b2));     // s3 = gi_n (no bias)
        h = (1.f - z) * n + z * h;
        if (g == 0) hs[(t + 1) & 1][r] = h;
        gcur = gnxt;
        wgbar();
    }
    if (g == 0) h_out[r] = h;
}

// ---------------------------------------------------------------------------
// K3: decoder GRU, quarter-split row-quad. 256 threads; lane = (row, part).
// inp==hid==o_prev for t>=1: q0=(Wih+Whh)_r, q1=(Wih+Whh)_z, q2=Wih_n,
// q3=Whh_n. Biases: b0=bih_r+bhh_r, b1=bih_z+bhh_z, b2=bih_n, b3=bhh_n
// (identical form at t=0). t=0 partials (inp=0, hid=h0) in the prologue.
// r=sig(v0), z=sig(v1), n=tanh(v2 + r*v3); o=(1-z)n+z*o.
// ---------------------------------------------------------------------------
__global__ void __launch_bounds__(256)
__attribute__((amdgpu_waves_per_eu(1, 1)))
k_dec(const float* __restrict__ Wih,
      const float* __restrict__ Whh,
      const float* __restrict__ bih,
      const float* __restrict__ bhh,
      const float* __restrict__ h0,
      float* __restrict__ outs) {
    int tid = threadIdx.x;
    int r = tid >> 2, g = tid & 3;
    __shared__ __align__(16) float hs[2][H];

    int col0 = g * 16;
    f32x2 w2[32];
    float pacc0 = 0.f, pacc1 = 0.f, pacc3 = 0.f;
    #pragma unroll
    for (int m = 0; m < 4; ++m) {
        float4 i0 = *(const float4*)(Wih + (size_t)r * H + col0 + 4 * m);
        float4 h0v = *(const float4*)(Whh + (size_t)r * H + col0 + 4 * m);
        float4 i1 = *(const float4*)(Wih + (size_t)(H + r) * H + col0 + 4 * m);
        float4 h1v = *(const float4*)(Whh + (size_t)(H + r) * H + col0 + 4 * m);
        float4 i2 = *(const float4*)(Wih + (size_t)(2 * H + r) * H + col0 + 4 * m);
        float4 h3v = *(const float4*)(Whh + (size_t)(2 * H + r) * H + col0 + 4 * m);
        float4 he = *(const float4*)(h0 + col0 + 4 * m);
        pacc0 += h0v.x * he.x + h0v.y * he.y + h0v.z * he.z + h0v.w * he.w;
        pacc1 += h1v.x * he.x + h1v.y * he.y + h1v.z * he.z + h1v.w * he.w;
        pacc3 += h3v.x * he.x + h3v.y * he.y + h3v.z * he.z + h3v.w * he.w;
        w2[2 * m]     = (f32x2){i0.x + h0v.x, i0.y + h0v.y};
        w2[2 * m + 1] = (f32x2){i0.z + h0v.z, i0.w + h0v.w};
        w2[8 + 2 * m]     = (f32x2){i1.x + h1v.x, i1.y + h1v.y};
        w2[8 + 2 * m + 1] = (f32x2){i1.z + h1v.z, i1.w + h1v.w};
        w2[16 + 2 * m]     = (f32x2){i2.x, i2.y};
        w2[16 + 2 * m + 1] = (f32x2){i2.z, i2.w};
        w2[24 + 2 * m]     = (f32x2){h3v.x, h3v.y};
        w2[24 + 2 * m + 1] = (f32x2){h3v.z, h3v.w};
    }
    #pragma unroll
    for (int m = 0; m < 32; ++m) PIN(w2[m]);
    float b0 = bih[r] + bhh[r];
    float b1 = bih[H + r] + bhh[H + r];
    float b2 = bih[2 * H + r];
    float b3 = bhh[2 * H + r];

    // t = 0: inp = 0, hid = h0
    float o;
    {
        float s0 = pacc0, s1 = pacc1, s2 = 0.f, s3 = pacc3;
        QUAD_REDUCE(s0); QUAD_REDUCE(s1); QUAD_REDUCE(s2); QUAD_REDUCE(s3);
        float rr = fsig(s0 + b0);
        float z  = fsig(s1 + b1);
        float n  = ftanh((s2 + b2) + rr * (s3 + b3));
        o = (1.f - z) * n + z * h0[r];
        if (g == 0) { outs[r] = o; hs[1][r] = o; }
    }
    wgbar();

    for (int t = 1; t < T; ++t) {
        f32x2 p0 = {0.f, 0.f}, p1 = {0.f, 0.f}, p2 = {0.f, 0.f}, p3 = {0.f, 0.f};
        QDOT(w2, hs[t & 1], p0, p1, p2, p3);
        float s0 = p0.x + p0.y, s1 = p1.x + p1.y;
        float s2 = p2.x + p2.y, s3 = p3.x + p3.y;
        QUAD_REDUCE(s0); QUAD_REDUCE(s1); QUAD_REDUCE(s2); QUAD_REDUCE(s3);
        float rr = fsig(s0 + b0);
        float z  = fsig(s1 + b1);
        float n  = ftanh((s2 + b2) + rr * (s3 + b3));
        o = (1.f - z) * n + z * o;
        if (g == 0) { outs[(size_t)t * H + r] = o; hs[(t + 1) & 1][r] = o; }
        wgbar();
    }
}

// ---------------------------------------------------------------------------
// K4: logits = outs @ W_out^T + b_out.  grid (197, 16) x 256 threads.
// ---------------------------------------------------------------------------
#define PT 128
__global__ void __launch_bounds__(256) k_proj(const float* __restrict__ outs,
                                              const float* __restrict__ Wout,
                                              const float* __restrict__ bout,
                                              float* __restrict__ out) {
    __shared__ __align__(16) float s[PT * H];
    int t0 = blockIdx.y * PT;
    {
        const float4* src = (const float4*)(outs + (size_t)t0 * H);
        for (int i = threadIdx.x; i < PT * H / 4; i += 256) ((float4*)s)[i] = src[i];
    }
    __syncthreads();
    int v = blockIdx.x * 256 + threadIdx.x;
    bool valid = v < VOCAB;
    float w[H];
    float bias = 0.0f;
    if (valid) {
        const float4* wr = (const float4*)(Wout + (size_t)v * H);
        #pragma unroll
        for (int k = 0; k < H / 4; ++k) {
            float4 f = wr[k];
            w[4 * k] = f.x; w[4 * k + 1] = f.y; w[4 * k + 2] = f.z; w[4 * k + 3] = f.w;
        }
        bias = bout[v];
    }
    for (int tt = 0; tt < PT; tt += 8) {
        float acc[8];
        #pragma unroll
        for (int u = 0; u < 8; ++u) acc[u] = bias;
        #pragma unroll
        for (int k = 0; k < H / 4; ++k) {
            #pragma unroll
            for (int u = 0; u < 8; ++u) {
                float4 hv = *(const float4*)&s[(tt + u) * H + 4 * k];
                acc[u] += w[4 * k] * hv.x + w[4 * k + 1] * hv.y + w[4 * k + 2] * hv.z + w[4 * k + 3] * hv.w;
            }
        }
        if (valid) {
            size_t base = (size_t)(t0 + tt) * VOCAB + v;
            #pragma unroll
            for (int u = 0; u < 8; ++u) out[base + (size_t)u * VOCAB] = acc[u];
        }
    }
}

extern "C" void kernel_launch(void* const* d_in, const int* in_sizes, int n_in,
                              void* d_out, int out_size, void* d_ws, size_t ws_size,
                              hipStream_t stream) {
    const int*   data    = (const int*)d_in[0];
    // d_in[1] = Type (ignored; reference takes the map branch)
    const float* emb     = (const float*)d_in[2];
    const float* Wih_enc = (const float*)d_in[3];
    const float* Whh_enc = (const float*)d_in[4];
    const float* bih_enc = (const float*)d_in[5];
    const float* bhh_enc = (const float*)d_in[6];
    const float* Wih_dec = (const float*)d_in[7];
    const float* Whh_dec = (const float*)d_in[8];
    const float* bih_dec = (const float*)d_in[9];
    const float* bhh_dec = (const float*)d_in[10];
    const float* W_out   = (const float*)d_in[11];
    const float* b_out   = (const float*)d_in[12];
    float* out = (float*)d_out;

    float* gi_enc = (float*)d_ws;            // T*G3 floats
    float* outs   = gi_enc + (size_t)T * G3; // T*H floats
    float* h_enc  = outs + (size_t)T * H;    // H floats

    k_embed_gi<<<T, G3, 0, stream>>>(data, emb, Wih_enc, bih_enc, gi_enc);
    k_enc<<<1, 256, 0, stream>>>(Whh_enc, bhh_enc, gi_enc, h_enc);
    k_dec<<<1, 256, 0, stream>>>(Wih_dec, Whh_dec, bih_dec, bhh_dec, h_enc, outs);
    dim3 pgrid((VOCAB + 255) / 256, T / PT);
    k_proj<<<pgrid, 256, 0, stream>>>(outs, W_out, b_out, out);
}